// Round 8
// baseline (3994.330 us; speedup 1.0000x reference)
//
#include <hip/hip_runtime.h>
#include <hip/hip_fp16.h>
#include <cstdint>

#define B_   128
#define T_   2048
#define DIN  5
#define H_   128
#define G3   384
#define D1   256
#define CH   256
#define NCH  (T_ / CH)   // 8

typedef _Float16 half8 __attribute__((ext_vector_type(8)));
typedef float f32x4 __attribute__((ext_vector_type(4)));

__device__ __forceinline__ float sigmoid_f(float x) {
    return __builtin_amdgcn_rcpf(1.0f + __expf(-x));
}
__device__ __forceinline__ float tanh_f(float x) {
    return 1.0f - 2.0f * __builtin_amdgcn_rcpf(__expf(2.0f * x) + 1.0f);
}
__device__ __forceinline__ unsigned long long pack4h(const float* h) {
    union { __half2 h2[2]; unsigned long long u; } pk;
    pk.h2[0] = __floats2half2_rn(h[0], h[1]);
    pk.h2[1] = __floats2half2_rn(h[2], h[3]);
    return pk.u;
}
__device__ __forceinline__ f32x4 h4_to_f(unsigned long long u) {
    union { unsigned long long u; __half2 h2[2]; } p; p.u = u;
    const float2 a = __half22float2(p.h2[0]);
    const float2 b = __half22float2(p.h2[1]);
    f32x4 r; r[0] = a.x; r[1] = a.y; r[2] = b.x; r[3] = b.y; return r;
}
// Barrier with LDS ordering only — no vmcnt(0) drain.
__device__ __forceinline__ void fast_barrier() {
    asm volatile("s_waitcnt lgkmcnt(0)\n\ts_barrier" ::: "memory");
}

// ---------------------------------------------------------------------------
// scan0: layer-0 GRU, MFMA. 16 blocks x 512 threads (8 waves), one chain per
// block; wave w owns gate-tile w. Split-K: 3 parallel MFMA chains (2,2,1)
// per gate instead of one 5-deep chain.
// ---------------------------------------------------------------------------
__global__ __launch_bounds__(512, 2) void scan0_mfma5(
    const float* __restrict__ seq,
    const float* __restrict__ wihf, const float* __restrict__ whhf,
    const float* __restrict__ bihf, const float* __restrict__ bhhf,
    const float* __restrict__ wihb, const float* __restrict__ whhb,
    const float* __restrict__ bihb, const float* __restrict__ bhhb,
    __half* __restrict__ y0)
{
    const int tid = threadIdx.x;
    const int w  = tid >> 6;
    const int l  = tid & 63;
    const int lo = l & 15;
    const int g  = l >> 4;
    const int dir = blockIdx.x >> 3;
    const int bg  = blockIdx.x & 7;

    const float* w_ih = dir ? wihb : wihf;
    const float* w_hh = dir ? whhb : whhf;
    const float* b_ih = dir ? bihb : bihf;
    const float* b_hh = dir ? bhhb : bhhf;

    __shared__ __align__(16) char smem[2 * 16 * 512];   // 16 KB

    half8 a_r[5], a_z[5], a_n[5], a_x;
    {
        const int grow = w * 16 + lo;
#pragma unroll
        for (int c = 0; c < 5; ++c) {
            half8 vr, vz, vn;
#pragma unroll
            for (int j = 0; j < 8; ++j) {
                const int k = c * 32 + g * 8 + j;
                float fr, fz, fn;
                if (k < 128) {
                    fr = w_hh[grow * H_ + k];
                    fz = w_hh[(128 + grow) * H_ + k];
                    fn = w_hh[(256 + grow) * H_ + k];
                } else if (k < 133) {
                    fr = w_ih[grow * DIN + (k - 128)];
                    fz = w_ih[(128 + grow) * DIN + (k - 128)];
                    fn = 0.f;
                } else if (k == 133) {
                    fr = b_ih[grow] + b_hh[grow];
                    fz = b_ih[128 + grow] + b_hh[128 + grow];
                    fn = b_hh[256 + grow];
                } else { fr = 0.f; fz = 0.f; fn = 0.f; }
                vr[j] = (_Float16)fr; vz[j] = (_Float16)fz; vn[j] = (_Float16)fn;
            }
            a_r[c] = vr; a_z[c] = vz; a_n[c] = vn;
        }
        half8 vx;
#pragma unroll
        for (int j = 0; j < 8; ++j) {
            const int k = 128 + g * 8 + j;
            float f = 0.f;
            if (k < 133)       f = w_ih[(256 + grow) * DIN + (k - 128)];
            else if (k == 133) f = b_ih[256 + grow];
            vx[j] = (_Float16)f;
        }
        a_x = vx;
    }

#pragma unroll
    for (int q = 0; q < 2; ++q) {
        f32x4 z = {0.f, 0.f, 0.f, 0.f};
        *reinterpret_cast<f32x4*>(smem + tid * 32 + q * 16) = z;
    }
    __syncthreads();
    if (tid < 32) {
        const int row = tid & 15, bu = tid >> 4;
        *(_Float16*)(smem + bu * 8192 + row * 512 + (266 ^ ((row & 7) << 4))) =
            (_Float16)1.0f;
    }
    const bool stager = tid < 80;
    const int sb = tid / 5, sd = tid % 5;
    const size_t seqbase = (size_t)(bg * 16 + sb) * T_ * DIN + sd;
    float x_t1 = 0.f;
    if (stager) {
        const int tt0 = dir ? (T_ - 1) : 0;
        const float x0 = seq[seqbase + (size_t)tt0 * DIN];
        *(_Float16*)(smem + sb * 512 + ((256 + 2 * sd) ^ ((sb & 7) << 4))) =
            (_Float16)x0;
        const int tt1 = dir ? (T_ - 2) : 1;
        x_t1 = seq[seqbase + (size_t)tt1 * DIN];
    }
    __syncthreads();

    float h_old[4];
#pragma unroll
    for (int q = 0; q < 4; ++q) h_old[q] = 0.f;

    for (int t = 0; t < T_; ++t) {
        char* cur = smem + (t & 1) * 8192;
        char* nxt = smem + ((t + 1) & 1) * 8192;

        if (stager)
            *(_Float16*)(nxt + sb * 512 + ((256 + 2 * sd) ^ ((sb & 7) << 4))) =
                (_Float16)x_t1;

        half8 bf[5];
#pragma unroll
        for (int c = 0; c < 5; ++c)
            bf[c] = *reinterpret_cast<const half8*>(
                cur + lo * 512 + ((c * 64 + g * 16) ^ ((lo & 7) << 4)));

        float x_t2 = 0.f;
        if (stager) {
            const int t2 = (t + 2 < T_) ? t + 2 : T_ - 1;
            const int tt2 = dir ? (T_ - 1 - t2) : t2;
            x_t2 = seq[seqbase + (size_t)tt2 * DIN];
        }

        // Split-K: 3 parallel chains (c0,c1) (c2,c3) (c4) per gate.
        f32x4 zr = {0.f, 0.f, 0.f, 0.f};
        f32x4 ra = zr, rb = zr, rc = zr;
        f32x4 za = zr, zb = zr, zc = zr;
        f32x4 na = zr, nb = zr, nc = zr;
        f32x4 accx;
        ra = __builtin_amdgcn_mfma_f32_16x16x32_f16(a_r[0], bf[0], ra, 0, 0, 0);
        za = __builtin_amdgcn_mfma_f32_16x16x32_f16(a_z[0], bf[0], za, 0, 0, 0);
        na = __builtin_amdgcn_mfma_f32_16x16x32_f16(a_n[0], bf[0], na, 0, 0, 0);
        rb = __builtin_amdgcn_mfma_f32_16x16x32_f16(a_r[2], bf[2], rb, 0, 0, 0);
        zb = __builtin_amdgcn_mfma_f32_16x16x32_f16(a_z[2], bf[2], zb, 0, 0, 0);
        nb = __builtin_amdgcn_mfma_f32_16x16x32_f16(a_n[2], bf[2], nb, 0, 0, 0);
        ra = __builtin_amdgcn_mfma_f32_16x16x32_f16(a_r[1], bf[1], ra, 0, 0, 0);
        za = __builtin_amdgcn_mfma_f32_16x16x32_f16(a_z[1], bf[1], za, 0, 0, 0);
        na = __builtin_amdgcn_mfma_f32_16x16x32_f16(a_n[1], bf[1], na, 0, 0, 0);
        rb = __builtin_amdgcn_mfma_f32_16x16x32_f16(a_r[3], bf[3], rb, 0, 0, 0);
        zb = __builtin_amdgcn_mfma_f32_16x16x32_f16(a_z[3], bf[3], zb, 0, 0, 0);
        nb = __builtin_amdgcn_mfma_f32_16x16x32_f16(a_n[3], bf[3], nb, 0, 0, 0);
        rc = __builtin_amdgcn_mfma_f32_16x16x32_f16(a_r[4], bf[4], rc, 0, 0, 0);
        zc = __builtin_amdgcn_mfma_f32_16x16x32_f16(a_z[4], bf[4], zc, 0, 0, 0);
        nc = __builtin_amdgcn_mfma_f32_16x16x32_f16(a_n[4], bf[4], nc, 0, 0, 0);
        accx = __builtin_amdgcn_mfma_f32_16x16x32_f16(a_x, bf[4], zr, 0, 0, 0);
        const f32x4 accr = (ra + rb) + rc;
        const f32x4 accz = (za + zb) + zc;
        const f32x4 accn = (na + nb) + nc;

        const int tt = dir ? (T_ - 1 - t) : t;
        {
            float hn[4];
#pragma unroll
            for (int q = 0; q < 4; ++q) {
                const float r = sigmoid_f(accr[q]);
                const float z = sigmoid_f(accz[q]);
                const float n = tanh_f(accx[q] + r * accn[q]);
                hn[q] = n + z * (h_old[q] - n);
                h_old[q] = hn[q];
            }
            const int j0 = w * 16 + g * 4;
            const unsigned long long pu = pack4h(hn);
            *reinterpret_cast<unsigned long long*>(
                &y0[((size_t)(bg * 16 + lo) * T_ + tt) * D1 + dir * H_ + j0]) = pu;
            *reinterpret_cast<unsigned long long*>(
                nxt + lo * 512 + ((2 * j0) ^ ((lo & 7) << 4))) = pu;
        }
        x_t1 = x_t2;
        fast_barrier();
    }
}

// ---------------------------------------------------------------------------
// gemm1: gx = y0(f16) @ W1f^T + b over an L-long time chunk (L = CH or T_).
// grid (B_*L/128, 6), 256 threads. log2L passed for row->batch/t mapping.
// ---------------------------------------------------------------------------
__global__ __launch_bounds__(256, 2) void gemm1_f16(
    const __half* __restrict__ A,   // y0h
    const float* __restrict__ W,    // 384 x 256
    const float* __restrict__ bias, // 384
    __half* __restrict__ C,         // (B*L) x 384, f16
    int c0, int log2L)
{
    __shared__ __align__(16) _Float16 As[128][32];
    __shared__ __align__(16) _Float16 Bs[64][32];
    const int tid = threadIdx.x;
    const int wave = tid >> 6, l = tid & 63;
    const int wm = wave >> 1, wn = wave & 1;
    const int lo = l & 15, g = l >> 4;
    const int m0 = blockIdx.x * 128, n0 = blockIdx.y * 64;
    const int lmask = (1 << log2L) - 1;

    f32x4 acc[4][2];
#pragma unroll
    for (int mt = 0; mt < 4; ++mt)
#pragma unroll
        for (int nt = 0; nt < 2; ++nt) {
            f32x4 z = {0.f, 0.f, 0.f, 0.f};
            acc[mt][nt] = z;
        }

    for (int kc = 0; kc < 256; kc += 32) {
#pragma unroll
        for (int r2 = 0; r2 < 2; ++r2) {
            const int idx = tid + r2 * 256;
            const int row = idx >> 2, seg = idx & 3;
            const int m = m0 + row, bb = m >> log2L, tlq = m & lmask;
            const __half* src = A + ((size_t)bb * T_ + c0 + tlq) * D1 + kc + seg * 8;
            *reinterpret_cast<uint4*>(&As[row][seg * 8]) =
                *reinterpret_cast<const uint4*>(src);
        }
        {
            const int row = tid >> 2, seg = tid & 3;
            const float* srcw = W + (size_t)(n0 + row) * D1 + kc + seg * 8;
            const float4 u0 = *reinterpret_cast<const float4*>(srcw);
            const float4 u1 = *reinterpret_cast<const float4*>(srcw + 4);
            half8 hv;
            hv[0] = (_Float16)u0.x; hv[1] = (_Float16)u0.y;
            hv[2] = (_Float16)u0.z; hv[3] = (_Float16)u0.w;
            hv[4] = (_Float16)u1.x; hv[5] = (_Float16)u1.y;
            hv[6] = (_Float16)u1.z; hv[7] = (_Float16)u1.w;
            *reinterpret_cast<half8*>(&Bs[row][seg * 8]) = hv;
        }
        __syncthreads();
        half8 af[4], bfr[2];
#pragma unroll
        for (int mt = 0; mt < 4; ++mt)
            af[mt] = *reinterpret_cast<half8*>(&As[wm * 64 + mt * 16 + lo][g * 8]);
#pragma unroll
        for (int nt = 0; nt < 2; ++nt)
            bfr[nt] = *reinterpret_cast<half8*>(&Bs[wn * 32 + nt * 16 + lo][g * 8]);
#pragma unroll
        for (int mt = 0; mt < 4; ++mt)
#pragma unroll
            for (int nt = 0; nt < 2; ++nt)
                acc[mt][nt] = __builtin_amdgcn_mfma_f32_16x16x32_f16(
                    af[mt], bfr[nt], acc[mt][nt], 0, 0, 0);
        __syncthreads();
    }
#pragma unroll
    for (int nt = 0; nt < 2; ++nt) {
        const int n = n0 + wn * 32 + nt * 16 + lo;
        const float bv = bias[n];
#pragma unroll
        for (int mt = 0; mt < 4; ++mt) {
            const int mrow = m0 + wm * 64 + mt * 16 + g * 4;
#pragma unroll
            for (int q = 0; q < 4; ++q)
                C[(size_t)(mrow + q) * G3 + n] = __float2half(acc[mt][nt][q] + bv);
        }
    }
}

// ---------------------------------------------------------------------------
// scan1: layer-1 forward over an L-long chunk. 8 blocks x 256 threads
// (4 waves, 2 gate-tiles each — best measured config). Split-K 2x2 chains.
// ---------------------------------------------------------------------------
__global__ __launch_bounds__(256, 1) void scan1_mfma5(
    const __half* __restrict__ gxc,  // [B][L][384] f16 (chunk-local t)
    const float* __restrict__ whh, const float* __restrict__ bhh,
    float* __restrict__ h1, int c, int L)
{
    const int tid = threadIdx.x;
    const int w = tid >> 6, l = tid & 63;
    const int lo = l & 15, g = l >> 4;
    const int grp = blockIdx.x;

    __shared__ __align__(16) char smem[2 * 16 * 256];   // 8 KB

    half8 a_r[2][4], a_z[2][4], a_n[2][4];
    float br[2][4], bz[2][4], bn[2][4];
#pragma unroll
    for (int i = 0; i < 2; ++i) {
        const int grow = (2 * w + i) * 16 + lo;
#pragma unroll
        for (int cc = 0; cc < 4; ++cc) {
            half8 vr, vz, vn;
#pragma unroll
            for (int j = 0; j < 8; ++j) {
                const int k = cc * 32 + g * 8 + j;
                vr[j] = (_Float16)whh[grow * H_ + k];
                vz[j] = (_Float16)whh[(128 + grow) * H_ + k];
                vn[j] = (_Float16)whh[(256 + grow) * H_ + k];
            }
            a_r[i][cc] = vr; a_z[i][cc] = vz; a_n[i][cc] = vn;
        }
#pragma unroll
        for (int q = 0; q < 4; ++q) {
            const int gq = (2 * w + i) * 16 + g * 4 + q;
            br[i][q] = bhh[gq];
            bz[i][q] = bhh[128 + gq];
            bn[i][q] = bhh[256 + gq];
        }
    }

#pragma unroll
    for (int q = 0; q < 2; ++q) {
        f32x4 z = {0.f, 0.f, 0.f, 0.f};
        *reinterpret_cast<f32x4*>(smem + tid * 32 + q * 16) = z;
    }
    __syncthreads();

    float h_old[2][4];
    if (c == 0) {
#pragma unroll
        for (int i = 0; i < 2; ++i)
#pragma unroll
            for (int q = 0; q < 4; ++q) h_old[i][q] = 0.f;
    } else {
#pragma unroll
        for (int i = 0; i < 2; ++i) {
            const int j0 = (2 * w + i) * 16 + g * 4;
            const f32x4 hv = *reinterpret_cast<const f32x4*>(
                &h1[(grp * 16 + lo) * H_ + j0]);
            float hn[4];
#pragma unroll
            for (int q = 0; q < 4; ++q) { h_old[i][q] = hv[q]; hn[q] = hv[q]; }
            *reinterpret_cast<unsigned long long*>(
                smem + lo * 256 + ((2 * j0) ^ ((lo & 7) << 4))) = pack4h(hn);
        }
    }
    __syncthreads();

    const __half* gxl = gxc + (size_t)(grp * 16 + lo) * L * G3;
    unsigned long long gxc_cur[6], gxc_nxt[6];
#pragma unroll
    for (int i = 0; i < 2; ++i) {
        const int gr0 = (2 * w + i) * 16 + g * 4;
        gxc_cur[i]     = *reinterpret_cast<const unsigned long long*>(gxl + gr0);
        gxc_cur[2 + i] = *reinterpret_cast<const unsigned long long*>(gxl + 128 + gr0);
        gxc_cur[4 + i] = *reinterpret_cast<const unsigned long long*>(gxl + 256 + gr0);
    }

    for (int t = 0; t < L; ++t) {
        char* curb = smem + (t & 1) * 4096;
        char* nxtb = smem + ((t + 1) & 1) * 4096;

        half8 bf[4];
#pragma unroll
        for (int cc = 0; cc < 4; ++cc)
            bf[cc] = *reinterpret_cast<const half8*>(
                curb + lo * 256 + ((cc * 64 + g * 16) ^ ((lo & 7) << 4)));

        const int tn = (t + 1 < L) ? t + 1 : t;
        const __half* p = gxl + (size_t)tn * G3;
#pragma unroll
        for (int i = 0; i < 2; ++i) {
            const int gr0 = (2 * w + i) * 16 + g * 4;
            gxc_nxt[i]     = *reinterpret_cast<const unsigned long long*>(p + gr0);
            gxc_nxt[2 + i] = *reinterpret_cast<const unsigned long long*>(p + 128 + gr0);
            gxc_nxt[4 + i] = *reinterpret_cast<const unsigned long long*>(p + 256 + gr0);
        }

        f32x4 accr[2], accz[2], accn[2];
#pragma unroll
        for (int i = 0; i < 2; ++i) {
            f32x4 zr = {0.f, 0.f, 0.f, 0.f};
            // Split-K: chains (c0,c1) and (c2,c3), then add.
            f32x4 rA = zr, rB = zr, zA = zr, zB = zr, nA = zr, nB = zr;
            rA = __builtin_amdgcn_mfma_f32_16x16x32_f16(a_r[i][0], bf[0], rA, 0, 0, 0);
            zA = __builtin_amdgcn_mfma_f32_16x16x32_f16(a_z[i][0], bf[0], zA, 0, 0, 0);
            nA = __builtin_amdgcn_mfma_f32_16x16x32_f16(a_n[i][0], bf[0], nA, 0, 0, 0);
            rB = __builtin_amdgcn_mfma_f32_16x16x32_f16(a_r[i][2], bf[2], rB, 0, 0, 0);
            zB = __builtin_amdgcn_mfma_f32_16x16x32_f16(a_z[i][2], bf[2], zB, 0, 0, 0);
            nB = __builtin_amdgcn_mfma_f32_16x16x32_f16(a_n[i][2], bf[2], nB, 0, 0, 0);
            rA = __builtin_amdgcn_mfma_f32_16x16x32_f16(a_r[i][1], bf[1], rA, 0, 0, 0);
            zA = __builtin_amdgcn_mfma_f32_16x16x32_f16(a_z[i][1], bf[1], zA, 0, 0, 0);
            nA = __builtin_amdgcn_mfma_f32_16x16x32_f16(a_n[i][1], bf[1], nA, 0, 0, 0);
            rB = __builtin_amdgcn_mfma_f32_16x16x32_f16(a_r[i][3], bf[3], rB, 0, 0, 0);
            zB = __builtin_amdgcn_mfma_f32_16x16x32_f16(a_z[i][3], bf[3], zB, 0, 0, 0);
            nB = __builtin_amdgcn_mfma_f32_16x16x32_f16(a_n[i][3], bf[3], nB, 0, 0, 0);
            accr[i] = rA + rB; accz[i] = zA + zB; accn[i] = nA + nB;
        }

#pragma unroll
        for (int i = 0; i < 2; ++i) {
            const f32x4 gr = h4_to_f(gxc_cur[i]);
            const f32x4 gz = h4_to_f(gxc_cur[2 + i]);
            const f32x4 gn = h4_to_f(gxc_cur[4 + i]);
            float hn[4];
#pragma unroll
            for (int q = 0; q < 4; ++q) {
                const float r = sigmoid_f(accr[i][q] + br[i][q] + gr[q]);
                const float z = sigmoid_f(accz[i][q] + bz[i][q] + gz[q]);
                const float n = tanh_f(gn[q] + r * (accn[i][q] + bn[i][q]));
                hn[q] = n + z * (h_old[i][q] - n);
                h_old[i][q] = hn[q];
            }
            const int j0 = (2 * w + i) * 16 + g * 4;
            *reinterpret_cast<unsigned long long*>(
                nxtb + lo * 256 + ((2 * j0) ^ ((lo & 7) << 4))) = pack4h(hn);
        }
#pragma unroll
        for (int i = 0; i < 6; ++i) gxc_cur[i] = gxc_nxt[i];
        fast_barrier();
    }

#pragma unroll
    for (int i = 0; i < 2; ++i) {
        const int j0 = (2 * w + i) * 16 + g * 4;
        f32x4 hv;
#pragma unroll
        for (int q = 0; q < 4; ++q) hv[q] = h_old[i][q];
        *reinterpret_cast<f32x4*>(&h1[(grp * 16 + lo) * H_ + j0]) = hv;
    }
}

// ---------------------------------------------------------------------------
// Layer-1 backward single step at t=T-1 (h0=0 -> gh=b_hh) + FC head.
// ---------------------------------------------------------------------------
__global__ __launch_bounds__(384, 1) void back1_fc(
    const __half* __restrict__ y0, const float* __restrict__ h1,
    const float* __restrict__ w_ih_1b, const float* __restrict__ b_ih_1b,
    const float* __restrict__ b_hh_1b,
    const float* __restrict__ fc_w, const float* __restrict__ fc_b,
    float* __restrict__ out)
{
    const int g = threadIdx.x;
    const int b = blockIdx.x;
    __shared__ float ylast[D1];
    __shared__ float pre_rz[2 * H_];
    __shared__ float gxn[H_], ghn[H_];
    __shared__ float hb[H_];
    __shared__ float red[H_];

    if (g < D1) ylast[g] = __half2float(y0[((size_t)b * T_ + (T_ - 1)) * D1 + g]);
    __syncthreads();

    float accb = b_ih_1b[g];
    const float* wrow = w_ih_1b + (size_t)g * D1;
#pragma unroll 8
    for (int k = 0; k < D1; k += 4) {
        const float4 v = *reinterpret_cast<const float4*>(&ylast[k]);
        const float4 wv = *reinterpret_cast<const float4*>(&wrow[k]);
        accb += v.x * wv.x + v.y * wv.y + v.z * wv.z + v.w * wv.w;
    }
    const float bh2 = b_hh_1b[g];
    if (g < 2 * H_) pre_rz[g] = accb + bh2;
    else            { gxn[g - 2 * H_] = accb; ghn[g - 2 * H_] = bh2; }
    __syncthreads();
    if (g < H_) {
        const float r = sigmoid_f(pre_rz[g]);
        const float z = sigmoid_f(pre_rz[g + H_]);
        const float n = tanh_f(gxn[g] + r * ghn[g]);
        hb[g] = (1.0f - z) * n;
    }
    __syncthreads();
    if (g < H_) red[g] = h1[b * H_ + g] * fc_w[g] + hb[g] * fc_w[H_ + g];
    __syncthreads();
    if (g == 0) {
        float s = fc_b[0];
#pragma unroll 8
        for (int k = 0; k < H_; ++k) s += red[k];
        out[b] = s;
    }
}

// ---------------------------------------------------------------------------
extern "C" void kernel_launch(void* const* d_in, const int* in_sizes, int n_in,
                              void* d_out, int out_size, void* d_ws, size_t ws_size,
                              hipStream_t stream)
{
    const float* seq      = (const float*)d_in[0];
    const float* w_ih_l0f = (const float*)d_in[1];
    const float* w_hh_l0f = (const float*)d_in[2];
    const float* b_ih_l0f = (const float*)d_in[3];
    const float* b_hh_l0f = (const float*)d_in[4];
    const float* w_ih_l0b = (const float*)d_in[5];
    const float* w_hh_l0b = (const float*)d_in[6];
    const float* b_ih_l0b = (const float*)d_in[7];
    const float* b_hh_l0b = (const float*)d_in[8];
    const float* w_ih_l1f = (const float*)d_in[9];
    const float* w_hh_l1f = (const float*)d_in[10];
    const float* b_ih_l1f = (const float*)d_in[11];
    const float* b_hh_l1f = (const float*)d_in[12];
    const float* w_ih_l1b = (const float*)d_in[13];
    // d_in[14] = w_hh_l1b unused (only t=T-1 of reversed bwd needed; h0=0).
    const float* b_ih_l1b = (const float*)d_in[15];
    const float* b_hh_l1b = (const float*)d_in[16];
    const float* fc_w     = (const float*)d_in[17];
    const float* fc_b     = (const float*)d_in[18];
    float* out = (float*)d_out;

    const size_t y0_bytes   = (size_t)B_ * T_ * D1 * sizeof(__half);   // 128 MiB
    const size_t gx_full_b  = (size_t)B_ * T_ * G3 * sizeof(__half);   // 192 MiB
    const size_t gx_chunk_b = (size_t)B_ * CH * G3 * sizeof(__half);   //  24 MiB
    const size_t h1_bytes   = (size_t)B_ * H_ * sizeof(float);

    __half* y0h = (__half*)d_ws;

    hipLaunchKernelGGL(scan0_mfma5, dim3(16), dim3(512), 0, stream,
        seq, w_ih_l0f, w_hh_l0f, b_ih_l0f, b_hh_l0f,
             w_ih_l0b, w_hh_l0b, b_ih_l0b, b_hh_l0b, y0h);

    if (ws_size >= y0_bytes + gx_full_b + h1_bytes) {
        // Full path: one GEMM over all T (saturates GPU), one scan1 launch.
        __half* gxc = (__half*)((char*)d_ws + y0_bytes);
        float*  h1  = (float*)((char*)d_ws + y0_bytes + gx_full_b);
        hipLaunchKernelGGL(gemm1_f16, dim3(B_ * T_ / 128, 6), dim3(256), 0, stream,
            y0h, w_ih_l1f, b_ih_l1f, gxc, 0, 11 /*log2(T_)*/);
        hipLaunchKernelGGL(scan1_mfma5, dim3(8), dim3(256), 0, stream,
            gxc, w_hh_l1f, b_hh_l1f, h1, 0, T_);
        hipLaunchKernelGGL(back1_fc, dim3(B_), dim3(384), 0, stream,
            y0h, h1, w_ih_l1b, b_ih_l1b, b_hh_l1b, fc_w, fc_b, out);
    } else {
        // Chunked fallback (proven at 152 MiB ws).
        __half* gxc = (__half*)((char*)d_ws + y0_bytes);
        float*  h1  = (float*)((char*)d_ws + y0_bytes + gx_chunk_b);
        for (int ci = 0; ci < NCH; ++ci) {
            hipLaunchKernelGGL(gemm1_f16, dim3(B_ * CH / 128, 6), dim3(256), 0, stream,
                y0h, w_ih_l1f, b_ih_l1f, gxc, ci * CH, 8 /*log2(CH)*/);
            hipLaunchKernelGGL(scan1_mfma5, dim3(8), dim3(256), 0, stream,
                gxc, w_hh_l1f, b_hh_l1f, h1, ci, CH);
        }
        hipLaunchKernelGGL(back1_fc, dim3(B_), dim3(384), 0, stream,
            y0h, h1, w_ih_l1b, b_ih_l1b, b_hh_l1b, fc_w, fc_b, out);
    }
}

// Round 9
// 3434.052 us; speedup vs baseline: 1.1632x; 1.1632x over previous
//
#include <hip/hip_runtime.h>
#include <hip/hip_fp16.h>
#include <cstdint>

#define B_   128
#define T_   2048
#define DIN  5
#define H_   128
#define G3   384
#define D1   256
#define CH   128
#define NCH  (T_ / CH)   // 16
#define LOG2CH 7

typedef _Float16 half8 __attribute__((ext_vector_type(8)));
typedef float f32x4 __attribute__((ext_vector_type(4)));

__device__ __forceinline__ float sigmoid_f(float x) {
    return __builtin_amdgcn_rcpf(1.0f + __expf(-x));
}
__device__ __forceinline__ float tanh_f(float x) {
    return 1.0f - 2.0f * __builtin_amdgcn_rcpf(__expf(2.0f * x) + 1.0f);
}
__device__ __forceinline__ unsigned long long pack4h(const float* h) {
    union { __half2 h2[2]; unsigned long long u; } pk;
    pk.h2[0] = __floats2half2_rn(h[0], h[1]);
    pk.h2[1] = __floats2half2_rn(h[2], h[3]);
    return pk.u;
}
__device__ __forceinline__ f32x4 h4_to_f(unsigned long long u) {
    union { unsigned long long u; __half2 h2[2]; } p; p.u = u;
    const float2 a = __half22float2(p.h2[0]);
    const float2 b = __half22float2(p.h2[1]);
    f32x4 r; r[0] = a.x; r[1] = a.y; r[2] = b.x; r[3] = b.y; return r;
}
// Barrier with LDS ordering only — no vmcnt(0) drain.
__device__ __forceinline__ void fast_barrier() {
    asm volatile("s_waitcnt lgkmcnt(0)\n\ts_barrier" ::: "memory");
}

// ---------------------------------------------------------------------------
// scan0: layer-0 GRU, MFMA. 16 blocks x 512 threads (8 waves), one chain per
// block; wave w owns gate-tile w. Sequential 5-deep MFMA chains (split-K
// regressed: chain latency is hidden by the 2nd wave/SIMD). r7-proven form.
// ---------------------------------------------------------------------------
__global__ __launch_bounds__(512, 2) void scan0_mfma4(
    const float* __restrict__ seq,
    const float* __restrict__ wihf, const float* __restrict__ whhf,
    const float* __restrict__ bihf, const float* __restrict__ bhhf,
    const float* __restrict__ wihb, const float* __restrict__ whhb,
    const float* __restrict__ bihb, const float* __restrict__ bhhb,
    __half* __restrict__ y0)
{
    const int tid = threadIdx.x;
    const int w  = tid >> 6;
    const int l  = tid & 63;
    const int lo = l & 15;
    const int g  = l >> 4;
    const int dir = blockIdx.x >> 3;
    const int bg  = blockIdx.x & 7;

    const float* w_ih = dir ? wihb : wihf;
    const float* w_hh = dir ? whhb : whhf;
    const float* b_ih = dir ? bihb : bihf;
    const float* b_hh = dir ? bhhb : bhhf;

    __shared__ __align__(16) char smem[2 * 16 * 512];   // 16 KB

    half8 a_r[5], a_z[5], a_n[5], a_x;
    {
        const int grow = w * 16 + lo;
#pragma unroll
        for (int c = 0; c < 5; ++c) {
            half8 vr, vz, vn;
#pragma unroll
            for (int j = 0; j < 8; ++j) {
                const int k = c * 32 + g * 8 + j;
                float fr, fz, fn;
                if (k < 128) {
                    fr = w_hh[grow * H_ + k];
                    fz = w_hh[(128 + grow) * H_ + k];
                    fn = w_hh[(256 + grow) * H_ + k];
                } else if (k < 133) {
                    fr = w_ih[grow * DIN + (k - 128)];
                    fz = w_ih[(128 + grow) * DIN + (k - 128)];
                    fn = 0.f;
                } else if (k == 133) {
                    fr = b_ih[grow] + b_hh[grow];
                    fz = b_ih[128 + grow] + b_hh[128 + grow];
                    fn = b_hh[256 + grow];
                } else { fr = 0.f; fz = 0.f; fn = 0.f; }
                vr[j] = (_Float16)fr; vz[j] = (_Float16)fz; vn[j] = (_Float16)fn;
            }
            a_r[c] = vr; a_z[c] = vz; a_n[c] = vn;
        }
        half8 vx;
#pragma unroll
        for (int j = 0; j < 8; ++j) {
            const int k = 128 + g * 8 + j;
            float f = 0.f;
            if (k < 133)       f = w_ih[(256 + grow) * DIN + (k - 128)];
            else if (k == 133) f = b_ih[256 + grow];
            vx[j] = (_Float16)f;
        }
        a_x = vx;
    }

#pragma unroll
    for (int q = 0; q < 2; ++q) {
        f32x4 z = {0.f, 0.f, 0.f, 0.f};
        *reinterpret_cast<f32x4*>(smem + tid * 32 + q * 16) = z;
    }
    __syncthreads();
    if (tid < 32) {
        const int row = tid & 15, bu = tid >> 4;
        *(_Float16*)(smem + bu * 8192 + row * 512 + (266 ^ ((row & 7) << 4))) =
            (_Float16)1.0f;
    }
    const bool stager = tid < 80;
    const int sb = tid / 5, sd = tid % 5;
    const size_t seqbase = (size_t)(bg * 16 + sb) * T_ * DIN + sd;
    float x_t1 = 0.f;
    if (stager) {
        const int tt0 = dir ? (T_ - 1) : 0;
        const float x0 = seq[seqbase + (size_t)tt0 * DIN];
        *(_Float16*)(smem + sb * 512 + ((256 + 2 * sd) ^ ((sb & 7) << 4))) =
            (_Float16)x0;
        const int tt1 = dir ? (T_ - 2) : 1;
        x_t1 = seq[seqbase + (size_t)tt1 * DIN];
    }
    __syncthreads();

    float h_old[4];
#pragma unroll
    for (int q = 0; q < 4; ++q) h_old[q] = 0.f;

    for (int t = 0; t < T_; ++t) {
        char* cur = smem + (t & 1) * 8192;
        char* nxt = smem + ((t + 1) & 1) * 8192;

        if (stager)
            *(_Float16*)(nxt + sb * 512 + ((256 + 2 * sd) ^ ((sb & 7) << 4))) =
                (_Float16)x_t1;

        half8 bf[5];
#pragma unroll
        for (int c = 0; c < 5; ++c)
            bf[c] = *reinterpret_cast<const half8*>(
                cur + lo * 512 + ((c * 64 + g * 16) ^ ((lo & 7) << 4)));

        float x_t2 = 0.f;
        if (stager) {
            const int t2 = (t + 2 < T_) ? t + 2 : T_ - 1;
            const int tt2 = dir ? (T_ - 1 - t2) : t2;
            x_t2 = seq[seqbase + (size_t)tt2 * DIN];
        }

        f32x4 zr = {0.f, 0.f, 0.f, 0.f};
        f32x4 accr = zr, accz = zr, accn = zr, accx;
#pragma unroll
        for (int c = 0; c < 5; ++c) {
            accr = __builtin_amdgcn_mfma_f32_16x16x32_f16(a_r[c], bf[c], accr, 0, 0, 0);
            accz = __builtin_amdgcn_mfma_f32_16x16x32_f16(a_z[c], bf[c], accz, 0, 0, 0);
            accn = __builtin_amdgcn_mfma_f32_16x16x32_f16(a_n[c], bf[c], accn, 0, 0, 0);
        }
        accx = __builtin_amdgcn_mfma_f32_16x16x32_f16(a_x, bf[4], zr, 0, 0, 0);

        const int tt = dir ? (T_ - 1 - t) : t;
        {
            float hn[4];
#pragma unroll
            for (int q = 0; q < 4; ++q) {
                const float r = sigmoid_f(accr[q]);
                const float z = sigmoid_f(accz[q]);
                const float n = tanh_f(accx[q] + r * accn[q]);
                hn[q] = n + z * (h_old[q] - n);
                h_old[q] = hn[q];
            }
            const int j0 = w * 16 + g * 4;
            const unsigned long long pu = pack4h(hn);
            *reinterpret_cast<unsigned long long*>(
                &y0[((size_t)(bg * 16 + lo) * T_ + tt) * D1 + dir * H_ + j0]) = pu;
            *reinterpret_cast<unsigned long long*>(
                nxt + lo * 512 + ((2 * j0) ^ ((lo & 7) << 4))) = pu;
        }
        x_t1 = x_t2;
        fast_barrier();
    }
}

// ---------------------------------------------------------------------------
// Fused layer-1 kernel: blocks 0-7 run scan1(chunk ci_scan) [r6-proven 4-wave
// form]; blocks 8..775 run gemm(chunk ci_gemm) concurrently on other CUs.
// Double-buffered gxc selected by chunk parity (never same buffer in one
// launch). scan1 blocks first so they dispatch without queuing behind gemm.
// ---------------------------------------------------------------------------
__device__ __forceinline__ void scan1_role(
    char* smem,
    const __half* __restrict__ gxc,
    const float* __restrict__ whh, const float* __restrict__ bhh,
    float* __restrict__ h1, int c)
{
    const int tid = threadIdx.x;
    const int w = tid >> 6, l = tid & 63;
    const int lo = l & 15, g = l >> 4;
    const int grp = blockIdx.x;      // 0..7

    half8 a_r[2][4], a_z[2][4], a_n[2][4];
    float br[2][4], bz[2][4], bn[2][4];
#pragma unroll
    for (int i = 0; i < 2; ++i) {
        const int grow = (2 * w + i) * 16 + lo;
#pragma unroll
        for (int cc = 0; cc < 4; ++cc) {
            half8 vr, vz, vn;
#pragma unroll
            for (int j = 0; j < 8; ++j) {
                const int k = cc * 32 + g * 8 + j;
                vr[j] = (_Float16)whh[grow * H_ + k];
                vz[j] = (_Float16)whh[(128 + grow) * H_ + k];
                vn[j] = (_Float16)whh[(256 + grow) * H_ + k];
            }
            a_r[i][cc] = vr; a_z[i][cc] = vz; a_n[i][cc] = vn;
        }
#pragma unroll
        for (int q = 0; q < 4; ++q) {
            const int gq = (2 * w + i) * 16 + g * 4 + q;
            br[i][q] = bhh[gq];
            bz[i][q] = bhh[128 + gq];
            bn[i][q] = bhh[256 + gq];
        }
    }

#pragma unroll
    for (int q = 0; q < 2; ++q) {
        f32x4 z = {0.f, 0.f, 0.f, 0.f};
        *reinterpret_cast<f32x4*>(smem + tid * 32 + q * 16) = z;
    }
    __syncthreads();

    float h_old[2][4];
    if (c == 0) {
#pragma unroll
        for (int i = 0; i < 2; ++i)
#pragma unroll
            for (int q = 0; q < 4; ++q) h_old[i][q] = 0.f;
    } else {
#pragma unroll
        for (int i = 0; i < 2; ++i) {
            const int j0 = (2 * w + i) * 16 + g * 4;
            const f32x4 hv = *reinterpret_cast<const f32x4*>(
                &h1[(grp * 16 + lo) * H_ + j0]);
            float hn[4];
#pragma unroll
            for (int q = 0; q < 4; ++q) { h_old[i][q] = hv[q]; hn[q] = hv[q]; }
            *reinterpret_cast<unsigned long long*>(
                smem + lo * 256 + ((2 * j0) ^ ((lo & 7) << 4))) = pack4h(hn);
        }
    }
    __syncthreads();

    const __half* gxl = gxc + (size_t)(grp * 16 + lo) * CH * G3;
    unsigned long long gxc_cur[6], gxc_nxt[6];
#pragma unroll
    for (int i = 0; i < 2; ++i) {
        const int gr0 = (2 * w + i) * 16 + g * 4;
        gxc_cur[i]     = *reinterpret_cast<const unsigned long long*>(gxl + gr0);
        gxc_cur[2 + i] = *reinterpret_cast<const unsigned long long*>(gxl + 128 + gr0);
        gxc_cur[4 + i] = *reinterpret_cast<const unsigned long long*>(gxl + 256 + gr0);
    }

    for (int t = 0; t < CH; ++t) {
        char* curb = smem + (t & 1) * 4096;
        char* nxtb = smem + ((t + 1) & 1) * 4096;

        half8 bf[4];
#pragma unroll
        for (int cc = 0; cc < 4; ++cc)
            bf[cc] = *reinterpret_cast<const half8*>(
                curb + lo * 256 + ((cc * 64 + g * 16) ^ ((lo & 7) << 4)));

        const int tn = (t + 1 < CH) ? t + 1 : t;
        const __half* p = gxl + (size_t)tn * G3;
#pragma unroll
        for (int i = 0; i < 2; ++i) {
            const int gr0 = (2 * w + i) * 16 + g * 4;
            gxc_nxt[i]     = *reinterpret_cast<const unsigned long long*>(p + gr0);
            gxc_nxt[2 + i] = *reinterpret_cast<const unsigned long long*>(p + 128 + gr0);
            gxc_nxt[4 + i] = *reinterpret_cast<const unsigned long long*>(p + 256 + gr0);
        }

        f32x4 accr[2], accz[2], accn[2];
#pragma unroll
        for (int i = 0; i < 2; ++i) {
            f32x4 zr = {0.f, 0.f, 0.f, 0.f};
            accr[i] = zr; accz[i] = zr; accn[i] = zr;
#pragma unroll
            for (int cc = 0; cc < 4; ++cc) {
                accr[i] = __builtin_amdgcn_mfma_f32_16x16x32_f16(a_r[i][cc], bf[cc], accr[i], 0, 0, 0);
                accz[i] = __builtin_amdgcn_mfma_f32_16x16x32_f16(a_z[i][cc], bf[cc], accz[i], 0, 0, 0);
                accn[i] = __builtin_amdgcn_mfma_f32_16x16x32_f16(a_n[i][cc], bf[cc], accn[i], 0, 0, 0);
            }
        }

#pragma unroll
        for (int i = 0; i < 2; ++i) {
            const f32x4 gr = h4_to_f(gxc_cur[i]);
            const f32x4 gz = h4_to_f(gxc_cur[2 + i]);
            const f32x4 gn = h4_to_f(gxc_cur[4 + i]);
            float hn[4];
#pragma unroll
            for (int q = 0; q < 4; ++q) {
                const float r = sigmoid_f(accr[i][q] + br[i][q] + gr[q]);
                const float z = sigmoid_f(accz[i][q] + bz[i][q] + gz[q]);
                const float n = tanh_f(gn[q] + r * (accn[i][q] + bn[i][q]));
                hn[q] = n + z * (h_old[i][q] - n);
                h_old[i][q] = hn[q];
            }
            const int j0 = (2 * w + i) * 16 + g * 4;
            *reinterpret_cast<unsigned long long*>(
                nxtb + lo * 256 + ((2 * j0) ^ ((lo & 7) << 4))) = pack4h(hn);
        }
#pragma unroll
        for (int i = 0; i < 6; ++i) gxc_cur[i] = gxc_nxt[i];
        fast_barrier();
    }

#pragma unroll
    for (int i = 0; i < 2; ++i) {
        const int j0 = (2 * w + i) * 16 + g * 4;
        f32x4 hv;
#pragma unroll
        for (int q = 0; q < 4; ++q) hv[q] = h_old[i][q];
        *reinterpret_cast<f32x4*>(&h1[(grp * 16 + lo) * H_ + j0]) = hv;
    }
}

__device__ __forceinline__ void gemm_role(
    char* smem, int rb,
    const __half* __restrict__ A, const float* __restrict__ W,
    const float* __restrict__ bias, __half* __restrict__ C, int c0)
{
    _Float16 (*As)[32] = reinterpret_cast<_Float16(*)[32]>(smem);          // 8 KB
    _Float16 (*Bs)[32] = reinterpret_cast<_Float16(*)[32]>(smem + 8192);   // 4 KB
    const int tid = threadIdx.x;
    const int wave = tid >> 6, l = tid & 63;
    const int wm = wave >> 1, wn = wave & 1;
    const int lo = l & 15, g = l >> 4;
    const int m0 = (rb & 127) * 128, n0 = (rb >> 7) * 64;

    f32x4 acc[4][2];
#pragma unroll
    for (int mt = 0; mt < 4; ++mt)
#pragma unroll
        for (int nt = 0; nt < 2; ++nt) {
            f32x4 z = {0.f, 0.f, 0.f, 0.f};
            acc[mt][nt] = z;
        }

    for (int kc = 0; kc < 256; kc += 32) {
#pragma unroll
        for (int r2 = 0; r2 < 2; ++r2) {
            const int idx = tid + r2 * 256;
            const int row = idx >> 2, seg = idx & 3;
            const int m = m0 + row, bb = m >> LOG2CH, tlq = m & (CH - 1);
            const __half* src = A + ((size_t)bb * T_ + c0 + tlq) * D1 + kc + seg * 8;
            *reinterpret_cast<uint4*>(&As[row][seg * 8]) =
                *reinterpret_cast<const uint4*>(src);
        }
        {
            const int row = tid >> 2, seg = tid & 3;
            const float* srcw = W + (size_t)(n0 + row) * D1 + kc + seg * 8;
            const float4 u0 = *reinterpret_cast<const float4*>(srcw);
            const float4 u1 = *reinterpret_cast<const float4*>(srcw + 4);
            half8 hv;
            hv[0] = (_Float16)u0.x; hv[1] = (_Float16)u0.y;
            hv[2] = (_Float16)u0.z; hv[3] = (_Float16)u0.w;
            hv[4] = (_Float16)u1.x; hv[5] = (_Float16)u1.y;
            hv[6] = (_Float16)u1.z; hv[7] = (_Float16)u1.w;
            *reinterpret_cast<half8*>(&Bs[row][seg * 8]) = hv;
        }
        __syncthreads();
        half8 af[4], bfr[2];
#pragma unroll
        for (int mt = 0; mt < 4; ++mt)
            af[mt] = *reinterpret_cast<half8*>(&As[wm * 64 + mt * 16 + lo][g * 8]);
#pragma unroll
        for (int nt = 0; nt < 2; ++nt)
            bfr[nt] = *reinterpret_cast<half8*>(&Bs[wn * 32 + nt * 16 + lo][g * 8]);
#pragma unroll
        for (int mt = 0; mt < 4; ++mt)
#pragma unroll
            for (int nt = 0; nt < 2; ++nt)
                acc[mt][nt] = __builtin_amdgcn_mfma_f32_16x16x32_f16(
                    af[mt], bfr[nt], acc[mt][nt], 0, 0, 0);
        __syncthreads();
    }
#pragma unroll
    for (int nt = 0; nt < 2; ++nt) {
        const int n = n0 + wn * 32 + nt * 16 + lo;
        const float bv = bias[n];
#pragma unroll
        for (int mt = 0; mt < 4; ++mt) {
            const int mrow = m0 + wm * 64 + mt * 16 + g * 4;
#pragma unroll
            for (int q = 0; q < 4; ++q)
                C[(size_t)(mrow + q) * G3 + n] = __float2half(acc[mt][nt][q] + bv);
        }
    }
}

__global__ __launch_bounds__(256, 1) void fused_l1(
    const __half* __restrict__ y0,
    const float* __restrict__ W1f, const float* __restrict__ b1f,
    __half* __restrict__ gbufA, __half* __restrict__ gbufB,
    const float* __restrict__ whh, const float* __restrict__ bhh,
    float* __restrict__ h1, int ci_scan, int ci_gemm)
{
    __shared__ __align__(16) char smem[12288];
    if (blockIdx.x < 8) {
        if (ci_scan >= 0) {
            const __half* gxc = (ci_scan & 1) ? gbufB : gbufA;
            scan1_role(smem, gxc, whh, bhh, h1, ci_scan);
        }
    } else {
        if (ci_gemm < NCH) {
            __half* gxc = (ci_gemm & 1) ? gbufB : gbufA;
            gemm_role(smem, (int)blockIdx.x - 8, y0, W1f, b1f, gxc, ci_gemm * CH);
        }
    }
}

// ---------------------------------------------------------------------------
// Layer-1 backward single step at t=T-1 (h0=0 -> gh=b_hh) + FC head.
// ---------------------------------------------------------------------------
__global__ __launch_bounds__(384, 1) void back1_fc(
    const __half* __restrict__ y0, const float* __restrict__ h1,
    const float* __restrict__ w_ih_1b, const float* __restrict__ b_ih_1b,
    const float* __restrict__ b_hh_1b,
    const float* __restrict__ fc_w, const float* __restrict__ fc_b,
    float* __restrict__ out)
{
    const int g = threadIdx.x;
    const int b = blockIdx.x;
    __shared__ float ylast[D1];
    __shared__ float pre_rz[2 * H_];
    __shared__ float gxn[H_], ghn[H_];
    __shared__ float hb[H_];
    __shared__ float red[H_];

    if (g < D1) ylast[g] = __half2float(y0[((size_t)b * T_ + (T_ - 1)) * D1 + g]);
    __syncthreads();

    float accb = b_ih_1b[g];
    const float* wrow = w_ih_1b + (size_t)g * D1;
#pragma unroll 8
    for (int k = 0; k < D1; k += 4) {
        const float4 v = *reinterpret_cast<const float4*>(&ylast[k]);
        const float4 wv = *reinterpret_cast<const float4*>(&wrow[k]);
        accb += v.x * wv.x + v.y * wv.y + v.z * wv.z + v.w * wv.w;
    }
    const float bh2 = b_hh_1b[g];
    if (g < 2 * H_) pre_rz[g] = accb + bh2;
    else            { gxn[g - 2 * H_] = accb; ghn[g - 2 * H_] = bh2; }
    __syncthreads();
    if (g < H_) {
        const float r = sigmoid_f(pre_rz[g]);
        const float z = sigmoid_f(pre_rz[g + H_]);
        const float n = tanh_f(gxn[g] + r * ghn[g]);
        hb[g] = (1.0f - z) * n;
    }
    __syncthreads();
    if (g < H_) red[g] = h1[b * H_ + g] * fc_w[g] + hb[g] * fc_w[H_ + g];
    __syncthreads();
    if (g == 0) {
        float s = fc_b[0];
#pragma unroll 8
        for (int k = 0; k < H_; ++k) s += red[k];
        out[b] = s;
    }
}

// ---------------------------------------------------------------------------
extern "C" void kernel_launch(void* const* d_in, const int* in_sizes, int n_in,
                              void* d_out, int out_size, void* d_ws, size_t ws_size,
                              hipStream_t stream)
{
    const float* seq      = (const float*)d_in[0];
    const float* w_ih_l0f = (const float*)d_in[1];
    const float* w_hh_l0f = (const float*)d_in[2];
    const float* b_ih_l0f = (const float*)d_in[3];
    const float* b_hh_l0f = (const float*)d_in[4];
    const float* w_ih_l0b = (const float*)d_in[5];
    const float* w_hh_l0b = (const float*)d_in[6];
    const float* b_ih_l0b = (const float*)d_in[7];
    const float* b_hh_l0b = (const float*)d_in[8];
    const float* w_ih_l1f = (const float*)d_in[9];
    const float* w_hh_l1f = (const float*)d_in[10];
    const float* b_ih_l1f = (const float*)d_in[11];
    const float* b_hh_l1f = (const float*)d_in[12];
    const float* w_ih_l1b = (const float*)d_in[13];
    // d_in[14] = w_hh_l1b unused (only t=T-1 of reversed bwd needed; h0=0).
    const float* b_ih_l1b = (const float*)d_in[15];
    const float* b_hh_l1b = (const float*)d_in[16];
    const float* fc_w     = (const float*)d_in[17];
    const float* fc_b     = (const float*)d_in[18];
    float* out = (float*)d_out;

    // ws layout (152.06 MiB, within proven budget):
    //   y0h   : 128 MiB
    //   gbufA :  12 MiB   (gx chunk, even chunks)
    //   gbufB :  12 MiB   (gx chunk, odd chunks)
    //   h1    :  64 KiB
    const size_t y0_bytes = (size_t)B_ * T_ * D1 * sizeof(__half);
    const size_t gx_bytes = (size_t)B_ * CH * G3 * sizeof(__half);
    __half* y0h   = (__half*)d_ws;
    __half* gbufA = (__half*)((char*)d_ws + y0_bytes);
    __half* gbufB = (__half*)((char*)d_ws + y0_bytes + gx_bytes);
    float*  h1    = (float*)((char*)d_ws + y0_bytes + 2 * gx_bytes);

    hipLaunchKernelGGL(scan0_mfma4, dim3(16), dim3(512), 0, stream,
        seq, w_ih_l0f, w_hh_l0f, b_ih_l0f, b_hh_l0f,
             w_ih_l0b, w_hh_l0b, b_ih_l0b, b_hh_l0b, y0h);

    // Software-pipelined layer 1: launch i runs scan1(i-1) || gemm(i).
    for (int i = 0; i <= NCH; ++i) {
        hipLaunchKernelGGL(fused_l1, dim3(8 + 768), dim3(256), 0, stream,
            y0h, w_ih_l1f, b_ih_l1f, gbufA, gbufB,
            w_hh_l1f, b_hh_l1f, h1, i - 1, i);
    }

    hipLaunchKernelGGL(back1_fc, dim3(B_), dim3(384), 0, stream,
        y0h, h1, w_ih_l1b, b_ih_l1b, b_hh_l1b, fc_w, fc_b, out);
}